// Round 1
// baseline (311.133 us; speedup 1.0000x reference)
//
#include <hip/hip_runtime.h>
#include <math.h>

// Problem constants
#define B_   8
#define T_   2048
#define V_   1024
#define C_   128
#define NB2  64     // 2*NB
#define L_   32     // chunk length for the linearized recurrence
#define NC_  64     // T_/L_

typedef _Float16 f16_t;
typedef f16_t f16x8 __attribute__((ext_vector_type(8)));
typedef float f32x4 __attribute__((ext_vector_type(4)));

__device__ __forceinline__ float sigmoidf_(float x){ return 1.0f/(1.0f+expf(-x)); }

// ---------------------------------------------------------------------------
// K0: weights. proj 0..2: softmax(basis@coeffs^T, axis=V) -> fp16,
//     TRANSPOSED (Wt[c][v]) for MFMA B-fragment reads.
//     proj 3: Wo (V,C) row-major fp16 (rows are B-fragments for out GEMM).
// fp16 is safe: softmax weights ~1e-3 >> 6.1e-5 min-normal; |logits| small.
// ---------------------------------------------------------------------------
__global__ __launch_bounds__(256) void weights_kernel(
    const float* __restrict__ basis,
    const float* __restrict__ qc, const float* __restrict__ kc,
    const float* __restrict__ vc, const float* __restrict__ oc,
    f16_t* __restrict__ Wo, f16_t* __restrict__ Wt)
{
  int blk  = blockIdx.x;
  int proj = blk >> 7;
  int c    = blk & 127;
  const float* coeffs = (proj==0)?qc : (proj==1)?kc : (proj==2)?vc : oc;

  __shared__ float coef[NB2];
  __shared__ float red[256];
  int tid = threadIdx.x;
  if (tid < NB2) coef[tid] = coeffs[c*NB2 + tid];
  __syncthreads();

  float l[4];
  for (int i=0;i<4;i++){
    int v = tid + i*256;
    const float4* bp = (const float4*)(basis + (size_t)v*NB2);
    float s = 0.f;
    #pragma unroll
    for (int f=0; f<NB2/4; f++){
      float4 b4 = bp[f];
      s += b4.x*coef[f*4+0] + b4.y*coef[f*4+1] + b4.z*coef[f*4+2] + b4.w*coef[f*4+3];
    }
    l[i] = s;
  }
  if (proj == 3){
    for (int i=0;i<4;i++){ int v = tid+i*256; Wo[(size_t)v*C_ + c] = (f16_t)l[i]; }
    return;
  }
  // softmax over V (1024 values per column c)
  float mx = fmaxf(fmaxf(l[0],l[1]), fmaxf(l[2],l[3]));
  red[tid] = mx; __syncthreads();
  for (int s=128; s>0; s>>=1){ if (tid<s) red[tid] = fmaxf(red[tid], red[tid+s]); __syncthreads(); }
  mx = red[0]; __syncthreads();
  float sum = 0.f;
  for (int i=0;i<4;i++) sum += expf(l[i]-mx);
  red[tid] = sum; __syncthreads();
  for (int s=128; s>0; s>>=1){ if (tid<s) red[tid] += red[tid+s]; __syncthreads(); }
  float inv = 1.0f/red[0];
  f16_t* tp = Wt + ((size_t)proj*C_ + c)*V_;
  for (int i=0;i<4;i++){
    int v = tid+i*256;
    tp[v] = (f16_t)(expf(l[i]-mx)*inv);
  }
}

// ---------------------------------------------------------------------------
// K1: q/k/v = x @ W, single-term fp16 MFMA (x cvt on the fly).
// 64x128 block tile, BK=64, 256 threads = 4 waves (2x2 of 32x64 wave tiles).
// REG-PREFETCH PIPELINE: issue tile kt+1 global loads BEFORE computing tile kt
// from LDS; the vmcnt drain at the post-compute barrier then overlaps the
// MFMA+ds_read phase instead of serializing ahead of it (latency-bound fix:
// MfmaUtil was 6.7%, all pipes idle).
// ---------------------------------------------------------------------------
#define BM 64
#define BN 128
#define BK 64
#define PADK 72   // LDS row stride in f16 (144 B, 16B-aligned, breaks pow2 banks)
#define NT_PROJ (V_/BK)   // 16

__global__ __launch_bounds__(256, 2) void proj_mfma_kernel(
    const float* __restrict__ x,
    const f16_t* __restrict__ Wt,
    float* __restrict__ out)
{
  const int M = B_*T_;
  int proj = blockIdx.y;
  int m0   = blockIdx.x * BM;
  float* op = out + (size_t)proj*M*C_;
  const f16_t* bp = Wt + (size_t)proj*C_*V_;

  __shared__ f16_t As[BM][PADK];
  __shared__ f16_t Bs[BN][PADK];

  int tid  = threadIdx.x;
  int lane = tid & 63;
  int w    = tid >> 6;
  int wm   = (w >> 1) * 32;
  int wn   = (w & 1) * 64;
  int lr   = lane & 15;
  int lg   = lane >> 4;

  // staging coordinates (constant per thread)
  int ar = tid >> 4;   // A row base (i*16 added per chunk)
  int aq = tid & 15;   // A float4 col
  int bn_ = tid >> 3;  // B row base (i*32 added per chunk)
  int bc = tid & 7;    // B 16B col

  const float* xbase = x + (size_t)m0*V_;

  f32x4 acc[2][4] = {};
  float4 xa[4];
  uint4  bv[4];

  // ---- load tile 0 into regs
  #pragma unroll
  for (int i=0;i<4;i++)
    xa[i] = *(const float4*)(xbase + (size_t)(ar + i*16)*V_ + aq*4);
  #pragma unroll
  for (int i=0;i<4;i++)
    bv[i] = *(const uint4*)(bp + (size_t)(bn_ + i*32)*V_ + bc*8);

#define PROJ_WRITE_TILE() do { \
    _Pragma("unroll") \
    for (int i=0;i<4;i++){ \
      union { f16_t h[4]; ushort4 u; } hh; \
      hh.h[0]=(f16_t)xa[i].x; hh.h[1]=(f16_t)xa[i].y; \
      hh.h[2]=(f16_t)xa[i].z; hh.h[3]=(f16_t)xa[i].w; \
      *(ushort4*)&As[ar + i*16][aq*4] = hh.u; \
    } \
    _Pragma("unroll") \
    for (int i=0;i<4;i++) \
      *(uint4*)&Bs[bn_ + i*32][bc*8] = bv[i]; \
  } while(0)

#define PROJ_COMPUTE_TILE() do { \
    _Pragma("unroll") \
    for (int kh=0; kh<2; kh++){ \
      f16x8 a[2]; \
      _Pragma("unroll") \
      for (int mt=0; mt<2; mt++) \
        a[mt] = *(f16x8*)&As[wm + mt*16 + lr][kh*32 + lg*8]; \
      _Pragma("unroll") \
      for (int nt=0; nt<4; nt++){ \
        f16x8 b = *(f16x8*)&Bs[wn + nt*16 + lr][kh*32 + lg*8]; \
        _Pragma("unroll") \
        for (int mt=0; mt<2; mt++) \
          acc[mt][nt] = __builtin_amdgcn_mfma_f32_16x16x32_f16(a[mt], b, acc[mt][nt], 0,0,0); \
      } \
    } \
  } while(0)

  PROJ_WRITE_TILE();
  __syncthreads();

  for (int kt=1; kt<NT_PROJ; kt++){
    // prefetch tile kt (global->regs, async w.r.t. the compute below)
    #pragma unroll
    for (int i=0;i<4;i++)
      xa[i] = *(const float4*)(xbase + (size_t)(ar + i*16)*V_ + kt*BK + aq*4);
    #pragma unroll
    for (int i=0;i<4;i++)
      bv[i] = *(const uint4*)(bp + (size_t)(bn_ + i*32)*V_ + kt*BK + bc*8);

    PROJ_COMPUTE_TILE();   // consumes LDS tile kt-1; load latency hides here
    __syncthreads();
    PROJ_WRITE_TILE();
    __syncthreads();
  }
  PROJ_COMPUTE_TILE();     // last tile

#undef PROJ_WRITE_TILE
#undef PROJ_COMPUTE_TILE

  // epilogue: C/D layout col=lane&15, row=(lane>>4)*4+reg
  #pragma unroll
  for (int mt=0; mt<2; mt++)
    #pragma unroll
    for (int nt=0; nt<4; nt++)
      #pragma unroll
      for (int r=0; r<4; r++){
        int row = m0 + wm + mt*16 + lg*4 + r;
        int col = wn + nt*16 + lr;
        op[(size_t)row*C_ + col] = acc[mt][nt][r];
      }
}

// ---------------------------------------------------------------------------
// K2: per-chunk KV summary: kv[b][ci][c][dd] = sum_j d^{L-1-j} k_j[c] v_j[dd]
// ---------------------------------------------------------------------------
__global__ __launch_bounds__(256) void kvsum_kernel(
    const float* __restrict__ k, const float* __restrict__ v,
    const float* __restrict__ dptr, float* __restrict__ kv)
{
  int ci = blockIdx.x, b = blockIdx.y;
  float d = sigmoidf_(dptr[0]);
  __shared__ float ks[L_][132];
  __shared__ float vs[L_][132];
  int tid = threadIdx.x;
  const float* kp = k + ((size_t)b*T_ + ci*L_)*C_;
  const float* vp = v + ((size_t)b*T_ + ci*L_)*C_;
  #pragma unroll
  for (int i=0;i<4;i++){
    int idx = tid + i*256;
    int j = idx >> 5, c4 = idx & 31;
    float w = powf(d, (float)(L_-1-j));
    float4 k4 = *(const float4*)(kp + (size_t)j*C_ + c4*4);
    k4.x*=w; k4.y*=w; k4.z*=w; k4.w*=w;
    *(float4*)&ks[j][c4*4] = k4;
    *(float4*)&vs[j][c4*4] = *(const float4*)(vp + (size_t)j*C_ + c4*4);
  }
  __syncthreads();
  int tc = tid >> 4, td = tid & 15;
  float acc[8][8] = {};
  for (int j=0;j<L_;j++){
    float kr[8], vr[8];
    *(float4*)&kr[0] = *(float4*)&ks[j][tc*8];
    *(float4*)&kr[4] = *(float4*)&ks[j][tc*8+4];
    *(float4*)&vr[0] = *(float4*)&vs[j][td*8];
    *(float4*)&vr[4] = *(float4*)&vs[j][td*8+4];
    #pragma unroll
    for (int a=0;a<8;a++)
      #pragma unroll
      for (int bb=0;bb<8;bb++) acc[a][bb] += kr[a]*vr[bb];
  }
  float* op = kv + ((size_t)b*NC_ + ci)*C_*C_;
  for (int a=0;a<8;a++)
    for (int b4=0;b4<2;b4++)
      *(float4*)(op + (size_t)(tc*8+a)*C_ + td*8 + b4*4) =
        make_float4(acc[a][b4*4],acc[a][b4*4+1],acc[a][b4*4+2],acc[a][b4*4+3]);
}

// ---------------------------------------------------------------------------
// K3: in-place exclusive scan over chunks
// ---------------------------------------------------------------------------
__global__ __launch_bounds__(256) void scan_kernel(
    float* __restrict__ kv, const float* __restrict__ dptr)
{
  int idx = blockIdx.x*256 + threadIdx.x;
  int b = idx >> 14, e = idx & 16383;
  float d  = sigmoidf_(dptr[0]);
  float dL = powf(d, (float)L_);
  float* p = kv + (size_t)b*NC_*C_*C_ + e;
  float m = 0.f;
  for (int i=0;i<NC_;i++){
    float s = p[(size_t)i*C_*C_];
    p[(size_t)i*C_*C_] = m;
    m = dL*m + s;
  }
}

// ---------------------------------------------------------------------------
// K4: per-chunk retrieved; epilogue writes ret as fp16 (feeds out MFMA)
// ---------------------------------------------------------------------------
__global__ __launch_bounds__(256) void intra_kernel(
    const float* __restrict__ q, const float* __restrict__ k,
    const float* __restrict__ v, const float* __restrict__ Minit,
    const float* __restrict__ dptr,
    f16_t* __restrict__ ret)
{
  int ci = blockIdx.x, b = blockIdx.y;
  int tid = threadIdx.x;
  float d = sigmoidf_(dptr[0]);
  __shared__ float qs[L_][132];
  __shared__ float kvs[L_][132];
  __shared__ float ps[L_][33];
  __shared__ float dpow[L_+1];
  if (tid <= L_) dpow[tid] = powf(d, (float)tid);

  const float* qp = q + ((size_t)b*T_ + ci*L_)*C_;
  const float* kp = k + ((size_t)b*T_ + ci*L_)*C_;
  const float* vp = v + ((size_t)b*T_ + ci*L_)*C_;
  #pragma unroll
  for (int i=0;i<4;i++){
    int idx = tid + i*256;
    int j = idx >> 5, c4 = idx & 31;
    *(float4*)&qs[j][c4*4]  = *(const float4*)(qp + (size_t)j*C_ + c4*4);
    *(float4*)&kvs[j][c4*4] = *(const float4*)(kp + (size_t)j*C_ + c4*4);
  }
  __syncthreads();

  {
    int tr = tid >> 4, tj = tid & 15;
    float s[2][2] = {};
    for (int c4=0;c4<32;c4++){
      float4 q4[2], k4[2];
      #pragma unroll
      for (int i=0;i<2;i++) q4[i] = *(float4*)&qs[tr*2+i][c4*4];
      #pragma unroll
      for (int i=0;i<2;i++) k4[i] = *(float4*)&kvs[tj*2+i][c4*4];
      #pragma unroll
      for (int a=0;a<2;a++)
        #pragma unroll
        for (int bb=0;bb<2;bb++)
          s[a][bb] += q4[a].x*k4[bb].x + q4[a].y*k4[bb].y + q4[a].z*k4[bb].z + q4[a].w*k4[bb].w;
    }
    #pragma unroll
    for (int a=0;a<2;a++)
      #pragma unroll
      for (int bb=0;bb<2;bb++){
        int r = tr*2+a, j = tj*2+bb;
        ps[r][j] = (j < r) ? s[a][bb]*dpow[r-1-j] : 0.f;
      }
  }
  __syncthreads();
  #pragma unroll
  for (int i=0;i<4;i++){
    int idx = tid + i*256;
    int j = idx >> 5, c4 = idx & 31;
    *(float4*)&kvs[j][c4*4] = *(const float4*)(vp + (size_t)j*C_ + c4*4);
  }
  __syncthreads();

  int tx = tid & 31, ty = tid >> 5;
  float acc[4][4] = {};
  const float* Mp = Minit + ((size_t)b*NC_ + ci)*C_*C_;
  for (int c=0;c<C_;c++){
    float4 m4 = *(const float4*)(Mp + (size_t)c*C_ + tx*4);
    #pragma unroll
    for (int r=0;r<4;r++){
      float qv = qs[ty*4+r][c];
      acc[r][0] += qv*m4.x; acc[r][1] += qv*m4.y; acc[r][2] += qv*m4.z; acc[r][3] += qv*m4.w;
    }
  }
  #pragma unroll
  for (int r=0;r<4;r++){
    float sc = dpow[ty*4+r];
    #pragma unroll
    for (int j=0;j<4;j++) acc[r][j] *= sc;
  }
  for (int j=0;j<L_;j++){
    float4 v4 = *(float4*)&kvs[j][tx*4];
    #pragma unroll
    for (int r=0;r<4;r++){
      float p = ps[ty*4+r][j];
      acc[r][0] += p*v4.x; acc[r][1] += p*v4.y; acc[r][2] += p*v4.z; acc[r][3] += p*v4.w;
    }
  }
  size_t rbase = ((size_t)b*T_ + ci*L_)*C_;
  for (int r=0;r<4;r++){
    union { f16_t h[4]; ushort4 u; } hh;
    #pragma unroll
    for (int j=0;j<4;j++) hh.h[j] = (f16_t)acc[r][j];
    *(ushort4*)(ret + rbase + (size_t)(ty*4+r)*C_ + tx*4) = hh.u;
  }
}

// ---------------------------------------------------------------------------
// K5: out = (ret @ Wo^T) * out_scale, single-term fp16 MFMA.
// M=16384, N=1024, K=128. BM=64, BN=128, kt loop 2x BK=64. grid (256,8).
// Same reg-prefetch pipeline as K1 (tile 1 loads issued during tile 0 MFMAs).
// ---------------------------------------------------------------------------
__global__ __launch_bounds__(256, 2) void out_mfma_kernel(
    const f16_t* __restrict__ A, const f16_t* __restrict__ Bw,
    const float* __restrict__ scl, float* __restrict__ out)
{
  int m0 = blockIdx.x * BM;
  int n0 = blockIdx.y * BN;
  float osc = scl[0];

  __shared__ f16_t As[BM][PADK];
  __shared__ f16_t Bs[BN][PADK];

  int tid  = threadIdx.x;
  int lane = tid & 63;
  int w    = tid >> 6;
  int wm   = (w >> 1) * 32;
  int wn   = (w & 1) * 64;
  int lr   = lane & 15;
  int lg   = lane >> 4;

  int rr = tid >> 3;   // row base for staging (i*32 added per chunk)
  int cc = tid & 7;    // 16B col

  f32x4 acc[2][4] = {};
  uint4 av[2], bv[4];

  // ---- load tile 0 into regs
  #pragma unroll
  for (int i=0;i<2;i++)
    av[i] = *(const uint4*)(A + (size_t)(m0 + rr + i*32)*C_ + cc*8);
  #pragma unroll
  for (int i=0;i<4;i++)
    bv[i] = *(const uint4*)(Bw + (size_t)(n0 + rr + i*32)*C_ + cc*8);

#define OUT_WRITE_TILE() do { \
    _Pragma("unroll") \
    for (int i=0;i<2;i++) \
      *(uint4*)&As[rr + i*32][cc*8] = av[i]; \
    _Pragma("unroll") \
    for (int i=0;i<4;i++) \
      *(uint4*)&Bs[rr + i*32][cc*8] = bv[i]; \
  } while(0)

#define OUT_COMPUTE_TILE() do { \
    _Pragma("unroll") \
    for (int kh=0; kh<2; kh++){ \
      f16x8 a[2]; \
      _Pragma("unroll") \
      for (int mt=0; mt<2; mt++) \
        a[mt] = *(f16x8*)&As[wm + mt*16 + lr][kh*32 + lg*8]; \
      _Pragma("unroll") \
      for (int nt=0; nt<4; nt++){ \
        f16x8 b = *(f16x8*)&Bs[wn + nt*16 + lr][kh*32 + lg*8]; \
        _Pragma("unroll") \
        for (int mt=0; mt<2; mt++) \
          acc[mt][nt] = __builtin_amdgcn_mfma_f32_16x16x32_f16(a[mt], b, acc[mt][nt], 0,0,0); \
      } \
    } \
  } while(0)

  OUT_WRITE_TILE();
  __syncthreads();

  // prefetch tile 1 while computing tile 0
  #pragma unroll
  for (int i=0;i<2;i++)
    av[i] = *(const uint4*)(A + (size_t)(m0 + rr + i*32)*C_ + BK + cc*8);
  #pragma unroll
  for (int i=0;i<4;i++)
    bv[i] = *(const uint4*)(Bw + (size_t)(n0 + rr + i*32)*C_ + BK + cc*8);

  OUT_COMPUTE_TILE();
  __syncthreads();
  OUT_WRITE_TILE();
  __syncthreads();
  OUT_COMPUTE_TILE();

#undef OUT_WRITE_TILE
#undef OUT_COMPUTE_TILE

  #pragma unroll
  for (int mt=0; mt<2; mt++)
    #pragma unroll
    for (int nt=0; nt<4; nt++)
      #pragma unroll
      for (int r=0; r<4; r++){
        int row = m0 + wm + mt*16 + lg*4 + r;
        int col = n0 + wn + nt*16 + lr;
        out[(size_t)row*V_ + col] = acc[mt][nt][r] * osc;
      }
}

// ---------------------------------------------------------------------------
extern "C" void kernel_launch(void* const* d_in, const int* in_sizes, int n_in,
                              void* d_out, int out_size, void* d_ws, size_t ws_size,
                              hipStream_t stream)
{
  const float* x     = (const float*)d_in[0];
  const float* basis = (const float*)d_in[1];
  const float* qc    = (const float*)d_in[2];
  const float* kc    = (const float*)d_in[3];
  const float* vc    = (const float*)d_in[4];
  const float* oc    = (const float*)d_in[5];
  const float* dptr  = (const float*)d_in[6];
  const float* sptr  = (const float*)d_in[7];
  float* out = (float*)d_out;
  float* ws  = (float*)d_ws;

  const size_t M = (size_t)B_*T_;
  // Workspace layout (offsets in FLOAT units; f16 arrays use 2 elems/float):
  //   Wo   f16 V*C      = 131072 h ->  65536 f   @ 0
  //   Wt   f16 3*C*V    = 393216 h -> 196608 f   @ 65536
  //   qkv  f32 3*M*C    = 6291456 f              @ 262144
  //   ret  f16 M*C      = 2097152 h -> 1048576 f @ 6553600
  //   kv   f32 B*NC*C*C = 8388608 f              @ 7602176
  //   end = 15990784 f = 64.0 MB
  f16_t* Wo  = (f16_t*)ws;
  f16_t* Wt  = (f16_t*)(ws + 65536);
  float* qkv = ws + 262144;
  f16_t* ret = (f16_t*)(ws + 6553600);
  float* kv  = ws + 7602176;

  float* q = qkv;
  float* k = qkv + M*C_;
  float* v = qkv + 2*M*C_;

  hipLaunchKernelGGL(weights_kernel, dim3(512), dim3(256), 0, stream,
                     basis, qc, kc, vc, oc, Wo, Wt);
  hipLaunchKernelGGL(proj_mfma_kernel, dim3(256,3), dim3(256), 0, stream,
                     x, Wt, qkv);
  hipLaunchKernelGGL(kvsum_kernel, dim3(NC_, B_), dim3(256), 0, stream, k, v, dptr, kv);
  hipLaunchKernelGGL(scan_kernel, dim3(512), dim3(256), 0, stream, kv, dptr);
  hipLaunchKernelGGL(intra_kernel, dim3(NC_, B_), dim3(256), 0, stream,
                     q, k, v, kv, dptr, ret);
  hipLaunchKernelGGL(out_mfma_kernel, dim3(256, 8), dim3(256), 0, stream,
                     ret, Wo, sptr, out);
}

// Round 2
// 254.389 us; speedup vs baseline: 1.2231x; 1.2231x over previous
//
#include <hip/hip_runtime.h>
#include <math.h>

// Problem constants
#define B_   8
#define T_   2048
#define V_   1024
#define C_   128
#define NB2  64     // 2*NB
#define L_   32     // chunk length for the linearized recurrence
#define NC_  64     // T_/L_

typedef _Float16 f16_t;
typedef f16_t f16x8 __attribute__((ext_vector_type(8)));
typedef float f32x4 __attribute__((ext_vector_type(4)));

__device__ __forceinline__ float sigmoidf_(float x){ return 1.0f/(1.0f+expf(-x)); }

// direct global->LDS DMA, 16 B per lane (dest must be linear: base + lane*16)
__device__ __forceinline__ void gload_lds16(const void* g, void* l){
  __builtin_amdgcn_global_load_lds(
      (const __attribute__((address_space(1))) uint32_t*)g,
      (__attribute__((address_space(3))) uint32_t*)l, 16, 0, 0);
}

// ---------------------------------------------------------------------------
// K0: weights. proj 0..2: softmax(basis@coeffs^T, axis=V) -> fp16,
//     TRANSPOSED (Wt[c][v]) for MFMA B-fragment reads.
//     proj 3: Wo (V,C) row-major fp16 (rows are B-fragments for out GEMM).
// fp16 is safe: softmax weights ~1e-3 >> 6.1e-5 min-normal; |logits| small.
// ---------------------------------------------------------------------------
__global__ __launch_bounds__(256) void weights_kernel(
    const float* __restrict__ basis,
    const float* __restrict__ qc, const float* __restrict__ kc,
    const float* __restrict__ vc, const float* __restrict__ oc,
    f16_t* __restrict__ Wo, f16_t* __restrict__ Wt)
{
  int blk  = blockIdx.x;
  int proj = blk >> 7;
  int c    = blk & 127;
  const float* coeffs = (proj==0)?qc : (proj==1)?kc : (proj==2)?vc : oc;

  __shared__ float coef[NB2];
  __shared__ float red[256];
  int tid = threadIdx.x;
  if (tid < NB2) coef[tid] = coeffs[c*NB2 + tid];
  __syncthreads();

  float l[4];
  for (int i=0;i<4;i++){
    int v = tid + i*256;
    const float4* bp = (const float4*)(basis + (size_t)v*NB2);
    float s = 0.f;
    #pragma unroll
    for (int f=0; f<NB2/4; f++){
      float4 b4 = bp[f];
      s += b4.x*coef[f*4+0] + b4.y*coef[f*4+1] + b4.z*coef[f*4+2] + b4.w*coef[f*4+3];
    }
    l[i] = s;
  }
  if (proj == 3){
    for (int i=0;i<4;i++){ int v = tid+i*256; Wo[(size_t)v*C_ + c] = (f16_t)l[i]; }
    return;
  }
  // softmax over V (1024 values per column c)
  float mx = fmaxf(fmaxf(l[0],l[1]), fmaxf(l[2],l[3]));
  red[tid] = mx; __syncthreads();
  for (int s=128; s>0; s>>=1){ if (tid<s) red[tid] = fmaxf(red[tid], red[tid+s]); __syncthreads(); }
  mx = red[0]; __syncthreads();
  float sum = 0.f;
  for (int i=0;i<4;i++) sum += expf(l[i]-mx);
  red[tid] = sum; __syncthreads();
  for (int s=128; s>0; s>>=1){ if (tid<s) red[tid] += red[tid+s]; __syncthreads(); }
  float inv = 1.0f/red[0];
  f16_t* tp = Wt + ((size_t)proj*C_ + c)*V_;
  for (int i=0;i<4;i++){
    int v = tid+i*256;
    tp[v] = (f16_t)(expf(l[i]-mx)*inv);
  }
}

// ---------------------------------------------------------------------------
// K1 (FUSED): q,k,v = x @ [Wq|Wk|Wv] in ONE pass over x.
// Round-0 read x 3x (192 MB) + Wt per-M-block (192 MB) through L2/L3 -> ~70us
// at ~5.6 TB/s effective hierarchy BW. Fusing cuts A-traffic 3x; B staged via
// global_load_lds (width 16, no VGPR round-trip -> no spill, cf. round-1's
// 162 MB scratch regression at VGPR_Count=48).
// 512 thr = 8 waves (2x4), wave tile 32x96, BM=64, N=384, BK=64, 16 K-iters.
// B LDS is linear (global_load_lds requirement); bank-swizzle achieved by
// XOR-ing the 16B-chunk index with (row&7) on the GLOBAL SOURCE address and
// applying the same XOR on the ds_read (involution, rule both-sides).
// LDS 57.6 KB, grid 256 = 1 block/CU, 8 waves/CU.
// ---------------------------------------------------------------------------
#define BM 64
#define BN 128
#define BK 64
#define PADK 72   // LDS row stride in f16 for A (144 B, breaks pow2 banks)
#define NF_  384  // 3*C
#define NT_PROJ (V_/BK)   // 16

__global__ __launch_bounds__(512, 1) void proj_fused_kernel(
    const float* __restrict__ x,
    const f16_t* __restrict__ Wt,   // [384][1024] f16 (= [3][C][V])
    float* __restrict__ out)        // [3][M][C]
{
  const int M = B_*T_;
  int m0 = blockIdx.x * BM;

  __shared__ __align__(16) f16_t As[BM][PADK];   // 9.2 KB
  __shared__ __align__(16) f16_t Bsh[NF_*BK];    // 48 KB, swizzled chunks

  int tid  = threadIdx.x;          // 0..511
  int lane = tid & 63;
  int w    = tid >> 6;             // 0..7
  int wm   = (w >> 2) * 32;        // 0,32
  int wn   = (w & 3) * 96;         // 0,96,192,288
  int lr   = lane & 15;
  int lg   = lane >> 4;

  const float* xbase = x + (size_t)m0*V_;

  f32x4 acc[2][6] = {};

  for (int kt = 0; kt < NT_PROJ; kt++){
    // ---- B: 384x64 f16 = 3072 16B chunks, 6 per thread, DMA to LDS.
    // LDS chunk ci (byte ci*16) receives global chunk (r, ch ^ (r&7)),
    // r = ci>>3 (row), ch = ci&7 (8 chunks of 16B per 128B row).
    #pragma unroll
    for (int i=0;i<6;i++){
      int ci = i*512 + tid;
      int r  = ci >> 3, ch = ci & 7;
      const f16_t* src = Wt + (size_t)r*V_ + kt*BK + ((ch ^ (r&7))<<3);
      gload_lds16(src, &Bsh[ci*8]);
    }
    // ---- A: 64x64 fp32 -> f16, 1024 float4 chunks, 2/thread (overlaps B DMA)
    #pragma unroll
    for (int i=0;i<2;i++){
      int ci = i*512 + tid;
      int row = ci >> 4, q = ci & 15;
      float4 xv = *(const float4*)(xbase + (size_t)row*V_ + kt*BK + q*4);
      union { f16_t h[4]; ushort4 u; } hh;
      hh.h[0]=(f16_t)xv.x; hh.h[1]=(f16_t)xv.y; hh.h[2]=(f16_t)xv.z; hh.h[3]=(f16_t)xv.w;
      *(ushort4*)&As[row][q*4] = hh.u;
    }
    __syncthreads();   // drains vmcnt (B DMA) + lgkm (A writes)

    #pragma unroll
    for (int kh=0; kh<2; kh++){
      f16x8 a[2];
      #pragma unroll
      for (int mt=0; mt<2; mt++)
        a[mt] = *(f16x8*)&As[wm + mt*16 + lr][kh*32 + lg*8];
      #pragma unroll
      for (int nt=0; nt<6; nt++){
        int n  = wn + nt*16 + lr;
        int c0 = kh*4 + lg;                       // logical 16B chunk in row
        f16x8 b = *(f16x8*)&Bsh[n*BK + ((c0 ^ (n&7))<<3)];
        #pragma unroll
        for (int mt=0; mt<2; mt++)
          acc[mt][nt] = __builtin_amdgcn_mfma_f32_16x16x32_f16(a[mt], b, acc[mt][nt], 0,0,0);
      }
    }
    __syncthreads();
  }

  // epilogue: C/D layout col=lane&15, row=(lane>>4)*4+reg; proj = n>>7
  #pragma unroll
  for (int mt=0; mt<2; mt++)
    #pragma unroll
    for (int nt=0; nt<6; nt++){
      int n   = wn + nt*16 + lr;
      int p   = n >> 7;
      int col = n & 127;
      float* op = out + (size_t)p*M*C_;
      #pragma unroll
      for (int r=0; r<4; r++){
        int row = m0 + wm + mt*16 + lg*4 + r;
        op[(size_t)row*C_ + col] = acc[mt][nt][r];
      }
    }
}

// ---------------------------------------------------------------------------
// K2: per-chunk KV summary: kv[b][ci][c][dd] = sum_j d^{L-1-j} k_j[c] v_j[dd]
// ---------------------------------------------------------------------------
__global__ __launch_bounds__(256) void kvsum_kernel(
    const float* __restrict__ k, const float* __restrict__ v,
    const float* __restrict__ dptr, float* __restrict__ kv)
{
  int ci = blockIdx.x, b = blockIdx.y;
  float d = sigmoidf_(dptr[0]);
  __shared__ float ks[L_][132];
  __shared__ float vs[L_][132];
  int tid = threadIdx.x;
  const float* kp = k + ((size_t)b*T_ + ci*L_)*C_;
  const float* vp = v + ((size_t)b*T_ + ci*L_)*C_;
  #pragma unroll
  for (int i=0;i<4;i++){
    int idx = tid + i*256;
    int j = idx >> 5, c4 = idx & 31;
    float w = powf(d, (float)(L_-1-j));
    float4 k4 = *(const float4*)(kp + (size_t)j*C_ + c4*4);
    k4.x*=w; k4.y*=w; k4.z*=w; k4.w*=w;
    *(float4*)&ks[j][c4*4] = k4;
    *(float4*)&vs[j][c4*4] = *(const float4*)(vp + (size_t)j*C_ + c4*4);
  }
  __syncthreads();
  int tc = tid >> 4, td = tid & 15;
  float acc[8][8] = {};
  for (int j=0;j<L_;j++){
    float kr[8], vr[8];
    *(float4*)&kr[0] = *(float4*)&ks[j][tc*8];
    *(float4*)&kr[4] = *(float4*)&ks[j][tc*8+4];
    *(float4*)&vr[0] = *(float4*)&vs[j][td*8];
    *(float4*)&vr[4] = *(float4*)&vs[j][td*8+4];
    #pragma unroll
    for (int a=0;a<8;a++)
      #pragma unroll
      for (int bb=0;bb<8;bb++) acc[a][bb] += kr[a]*vr[bb];
  }
  float* op = kv + ((size_t)b*NC_ + ci)*C_*C_;
  for (int a=0;a<8;a++)
    for (int b4=0;b4<2;b4++)
      *(float4*)(op + (size_t)(tc*8+a)*C_ + td*8 + b4*4) =
        make_float4(acc[a][b4*4],acc[a][b4*4+1],acc[a][b4*4+2],acc[a][b4*4+3]);
}

// ---------------------------------------------------------------------------
// K3: in-place exclusive scan over chunks
// ---------------------------------------------------------------------------
__global__ __launch_bounds__(256) void scan_kernel(
    float* __restrict__ kv, const float* __restrict__ dptr)
{
  int idx = blockIdx.x*256 + threadIdx.x;
  int b = idx >> 14, e = idx & 16383;
  float d  = sigmoidf_(dptr[0]);
  float dL = powf(d, (float)L_);
  float* p = kv + (size_t)b*NC_*C_*C_ + e;
  float m = 0.f;
  for (int i=0;i<NC_;i++){
    float s = p[(size_t)i*C_*C_];
    p[(size_t)i*C_*C_] = m;
    m = dL*m + s;
  }
}

// ---------------------------------------------------------------------------
// K4: per-chunk retrieved; epilogue writes ret as fp16 (feeds out MFMA)
// ---------------------------------------------------------------------------
__global__ __launch_bounds__(256) void intra_kernel(
    const float* __restrict__ q, const float* __restrict__ k,
    const float* __restrict__ v, const float* __restrict__ Minit,
    const float* __restrict__ dptr,
    f16_t* __restrict__ ret)
{
  int ci = blockIdx.x, b = blockIdx.y;
  int tid = threadIdx.x;
  float d = sigmoidf_(dptr[0]);
  __shared__ float qs[L_][132];
  __shared__ float kvs[L_][132];
  __shared__ float ps[L_][33];
  __shared__ float dpow[L_+1];
  if (tid <= L_) dpow[tid] = powf(d, (float)tid);

  const float* qp = q + ((size_t)b*T_ + ci*L_)*C_;
  const float* kp = k + ((size_t)b*T_ + ci*L_)*C_;
  const float* vp = v + ((size_t)b*T_ + ci*L_)*C_;
  #pragma unroll
  for (int i=0;i<4;i++){
    int idx = tid + i*256;
    int j = idx >> 5, c4 = idx & 31;
    *(float4*)&qs[j][c4*4]  = *(const float4*)(qp + (size_t)j*C_ + c4*4);
    *(float4*)&kvs[j][c4*4] = *(const float4*)(kp + (size_t)j*C_ + c4*4);
  }
  __syncthreads();

  {
    int tr = tid >> 4, tj = tid & 15;
    float s[2][2] = {};
    for (int c4=0;c4<32;c4++){
      float4 q4[2], k4[2];
      #pragma unroll
      for (int i=0;i<2;i++) q4[i] = *(float4*)&qs[tr*2+i][c4*4];
      #pragma unroll
      for (int i=0;i<2;i++) k4[i] = *(float4*)&kvs[tj*2+i][c4*4];
      #pragma unroll
      for (int a=0;a<2;a++)
        #pragma unroll
        for (int bb=0;bb<2;bb++)
          s[a][bb] += q4[a].x*k4[bb].x + q4[a].y*k4[bb].y + q4[a].z*k4[bb].z + q4[a].w*k4[bb].w;
    }
    #pragma unroll
    for (int a=0;a<2;a++)
      #pragma unroll
      for (int bb=0;bb<2;bb++){
        int r = tr*2+a, j = tj*2+bb;
        ps[r][j] = (j < r) ? s[a][bb]*dpow[r-1-j] : 0.f;
      }
  }
  __syncthreads();
  #pragma unroll
  for (int i=0;i<4;i++){
    int idx = tid + i*256;
    int j = idx >> 5, c4 = idx & 31;
    *(float4*)&kvs[j][c4*4] = *(const float4*)(vp + (size_t)j*C_ + c4*4);
  }
  __syncthreads();

  int tx = tid & 31, ty = tid >> 5;
  float acc[4][4] = {};
  const float* Mp = Minit + ((size_t)b*NC_ + ci)*C_*C_;
  for (int c=0;c<C_;c++){
    float4 m4 = *(const float4*)(Mp + (size_t)c*C_ + tx*4);
    #pragma unroll
    for (int r=0;r<4;r++){
      float qv = qs[ty*4+r][c];
      acc[r][0] += qv*m4.x; acc[r][1] += qv*m4.y; acc[r][2] += qv*m4.z; acc[r][3] += qv*m4.w;
    }
  }
  #pragma unroll
  for (int r=0;r<4;r++){
    float sc = dpow[ty*4+r];
    #pragma unroll
    for (int j=0;j<4;j++) acc[r][j] *= sc;
  }
  for (int j=0;j<L_;j++){
    float4 v4 = *(float4*)&kvs[j][tx*4];
    #pragma unroll
    for (int r=0;r<4;r++){
      float p = ps[ty*4+r][j];
      acc[r][0] += p*v4.x; acc[r][1] += p*v4.y; acc[r][2] += p*v4.z; acc[r][3] += p*v4.w;
    }
  }
  size_t rbase = ((size_t)b*T_ + ci*L_)*C_;
  for (int r=0;r<4;r++){
    union { f16_t h[4]; ushort4 u; } hh;
    #pragma unroll
    for (int j=0;j<4;j++) hh.h[j] = (f16_t)acc[r][j];
    *(ushort4*)(ret + rbase + (size_t)(ty*4+r)*C_ + tx*4) = hh.u;
  }
}

// ---------------------------------------------------------------------------
// K5: out = (ret @ Wo^T) * out_scale, single-term fp16 MFMA.
// M=16384, N=1024, K=128. BM=64, BN=128, kt loop 2x BK=64. grid (256,8).
// (round-0 form; reg-prefetch variant reverted — it spilled to scratch)
// ---------------------------------------------------------------------------
__global__ __launch_bounds__(256, 2) void out_mfma_kernel(
    const f16_t* __restrict__ A, const f16_t* __restrict__ Bw,
    const float* __restrict__ scl, float* __restrict__ out)
{
  int m0 = blockIdx.x * BM;
  int n0 = blockIdx.y * BN;
  float osc = scl[0];

  __shared__ f16_t As[BM][PADK];
  __shared__ f16_t Bs[BN][PADK];

  int tid  = threadIdx.x;
  int lane = tid & 63;
  int w    = tid >> 6;
  int wm   = (w >> 1) * 32;
  int wn   = (w & 1) * 64;
  int lr   = lane & 15;
  int lg   = lane >> 4;

  f32x4 acc[2][4] = {};

  for (int kt = 0; kt < 2; kt++){
    // stage A: 64x64 f16 = 512 16B chunks, 2/thread
    #pragma unroll
    for (int i=0;i<2;i++){
      int ci = tid + i*256;
      int row = ci >> 3, ch = ci & 7;
      *(uint4*)&As[row][ch*8] = *(const uint4*)(A + (size_t)(m0+row)*C_ + kt*BK + ch*8);
    }
    // stage B: 128x64 f16 = 1024 16B chunks, 4/thread
    #pragma unroll
    for (int i=0;i<4;i++){
      int ci = tid + i*256;
      int n = ci >> 3, ch = ci & 7;
      *(uint4*)&Bs[n][ch*8] = *(const uint4*)(Bw + (size_t)(n0+n)*C_ + kt*BK + ch*8);
    }
    __syncthreads();

    #pragma unroll
    for (int kh=0; kh<2; kh++){
      f16x8 a[2];
      #pragma unroll
      for (int mt=0; mt<2; mt++)
        a[mt] = *(f16x8*)&As[wm + mt*16 + lr][kh*32 + lg*8];
      #pragma unroll
      for (int nt=0; nt<4; nt++){
        f16x8 b = *(f16x8*)&Bs[wn + nt*16 + lr][kh*32 + lg*8];
        #pragma unroll
        for (int mt=0; mt<2; mt++)
          acc[mt][nt] = __builtin_amdgcn_mfma_f32_16x16x32_f16(a[mt], b, acc[mt][nt], 0,0,0);
      }
    }
    __syncthreads();
  }

  #pragma unroll
  for (int mt=0; mt<2; mt++)
    #pragma unroll
    for (int nt=0; nt<4; nt++)
      #pragma unroll
      for (int r=0; r<4; r++){
        int row = m0 + wm + mt*16 + lg*4 + r;
        int col = n0 + wn + nt*16 + lr;
        out[(size_t)row*V_ + col] = acc[mt][nt][r] * osc;
      }
}

// ---------------------------------------------------------------------------
extern "C" void kernel_launch(void* const* d_in, const int* in_sizes, int n_in,
                              void* d_out, int out_size, void* d_ws, size_t ws_size,
                              hipStream_t stream)
{
  const float* x     = (const float*)d_in[0];
  const float* basis = (const float*)d_in[1];
  const float* qc    = (const float*)d_in[2];
  const float* kc    = (const float*)d_in[3];
  const float* vc    = (const float*)d_in[4];
  const float* oc    = (const float*)d_in[5];
  const float* dptr  = (const float*)d_in[6];
  const float* sptr  = (const float*)d_in[7];
  float* out = (float*)d_out;
  float* ws  = (float*)d_ws;

  const size_t M = (size_t)B_*T_;
  // Workspace layout (offsets in FLOAT units; f16 arrays use 2 elems/float):
  //   Wo   f16 V*C      = 131072 h ->  65536 f   @ 0
  //   Wt   f16 3*C*V    = 393216 h -> 196608 f   @ 65536
  //   qkv  f32 3*M*C    = 6291456 f              @ 262144
  //   ret  f16 M*C      = 2097152 h -> 1048576 f @ 6553600
  //   kv   f32 B*NC*C*C = 8388608 f              @ 7602176
  //   end = 15990784 f = 64.0 MB
  f16_t* Wo  = (f16_t*)ws;
  f16_t* Wt  = (f16_t*)(ws + 65536);
  float* qkv = ws + 262144;
  f16_t* ret = (f16_t*)(ws + 6553600);
  float* kv  = ws + 7602176;

  float* q = qkv;
  float* k = qkv + M*C_;
  float* v = qkv + 2*M*C_;

  hipLaunchKernelGGL(weights_kernel, dim3(512), dim3(256), 0, stream,
                     basis, qc, kc, vc, oc, Wo, Wt);
  hipLaunchKernelGGL(proj_fused_kernel, dim3(256), dim3(512), 0, stream,
                     x, Wt, qkv);
  hipLaunchKernelGGL(kvsum_kernel, dim3(NC_, B_), dim3(256), 0, stream, k, v, dptr, kv);
  hipLaunchKernelGGL(scan_kernel, dim3(512), dim3(256), 0, stream, kv, dptr);
  hipLaunchKernelGGL(intra_kernel, dim3(NC_, B_), dim3(256), 0, stream,
                     q, k, v, kv, dptr, ret);
  hipLaunchKernelGGL(out_mfma_kernel, dim3(256, 8), dim3(256), 0, stream,
                     ret, Wo, sptr, out);
}

// Round 4
// 249.656 us; speedup vs baseline: 1.2462x; 1.0190x over previous
//
#include <hip/hip_runtime.h>
#include <math.h>

// Problem constants
#define B_   8
#define T_   2048
#define V_   1024
#define C_   128
#define NB2  64     // 2*NB
#define L_   32     // chunk length for the linearized recurrence
#define NC_  64     // T_/L_

typedef _Float16 f16_t;
typedef f16_t f16x8 __attribute__((ext_vector_type(8)));
typedef float f32x4 __attribute__((ext_vector_type(4)));

__device__ __forceinline__ float sigmoidf_(float x){ return 1.0f/(1.0f+expf(-x)); }

// direct global->LDS DMA, 16 B per lane (dest must be linear: base + lane*16)
__device__ __forceinline__ void gload_lds16(const void* g, void* l){
  __builtin_amdgcn_global_load_lds(
      (const __attribute__((address_space(1))) uint32_t*)g,
      (__attribute__((address_space(3))) uint32_t*)l, 16, 0, 0);
}

// ---------------------------------------------------------------------------
// K0: weights. proj 0..2: softmax(basis@coeffs^T, axis=V) -> fp16,
//     TRANSPOSED (Wt[c][v]) for MFMA B-fragment reads.
//     proj 3: Wo (V,C) row-major fp16 (rows are B-fragments for out GEMM).
// ---------------------------------------------------------------------------
__global__ __launch_bounds__(256) void weights_kernel(
    const float* __restrict__ basis,
    const float* __restrict__ qc, const float* __restrict__ kc,
    const float* __restrict__ vc, const float* __restrict__ oc,
    f16_t* __restrict__ Wo, f16_t* __restrict__ Wt)
{
  int blk  = blockIdx.x;
  int proj = blk >> 7;
  int c    = blk & 127;
  const float* coeffs = (proj==0)?qc : (proj==1)?kc : (proj==2)?vc : oc;

  __shared__ float coef[NB2];
  __shared__ float red[256];
  int tid = threadIdx.x;
  if (tid < NB2) coef[tid] = coeffs[c*NB2 + tid];
  __syncthreads();

  float l[4];
  for (int i=0;i<4;i++){
    int v = tid + i*256;
    const float4* bp = (const float4*)(basis + (size_t)v*NB2);
    float s = 0.f;
    #pragma unroll
    for (int f=0; f<NB2/4; f++){
      float4 b4 = bp[f];
      s += b4.x*coef[f*4+0] + b4.y*coef[f*4+1] + b4.z*coef[f*4+2] + b4.w*coef[f*4+3];
    }
    l[i] = s;
  }
  if (proj == 3){
    for (int i=0;i<4;i++){ int v = tid+i*256; Wo[(size_t)v*C_ + c] = (f16_t)l[i]; }
    return;
  }
  float mx = fmaxf(fmaxf(l[0],l[1]), fmaxf(l[2],l[3]));
  red[tid] = mx; __syncthreads();
  for (int s=128; s>0; s>>=1){ if (tid<s) red[tid] = fmaxf(red[tid], red[tid+s]); __syncthreads(); }
  mx = red[0]; __syncthreads();
  float sum = 0.f;
  for (int i=0;i<4;i++) sum += expf(l[i]-mx);
  red[tid] = sum; __syncthreads();
  for (int s=128; s>0; s>>=1){ if (tid<s) red[tid] += red[tid+s]; __syncthreads(); }
  float inv = 1.0f/red[0];
  f16_t* tp = Wt + ((size_t)proj*C_ + c)*V_;
  for (int i=0;i<4;i++){
    int v = tid+i*256;
    tp[v] = (f16_t)(expf(l[i]-mx)*inv);
  }
}

// ---------------------------------------------------------------------------
// K1 (FUSED): q,k,v = x @ [Wq|Wk|Wv] in ONE pass over x.
// 512 thr = 8 waves (2x4), wave tile 32x96, BM=64, N=384, BK=64, 16 K-iters.
// B staged via global_load_lds (linear LDS, XOR-swizzled source + same XOR on
// ds_read). LDS 57.6 KB, grid 256 = 1 block/CU.
// ---------------------------------------------------------------------------
#define BM 64
#define BN 128
#define BK 64
#define PADK 72   // LDS row stride in f16 for A (144 B, breaks pow2 banks)
#define NF_  384  // 3*C
#define NT_PROJ (V_/BK)   // 16

__global__ __launch_bounds__(512, 1) void proj_fused_kernel(
    const float* __restrict__ x,
    const f16_t* __restrict__ Wt,   // [384][1024] f16 (= [3][C][V])
    float* __restrict__ out)        // [3][M][C]
{
  const int M = B_*T_;
  int m0 = blockIdx.x * BM;

  __shared__ __align__(16) f16_t As[BM][PADK];   // 9.2 KB
  __shared__ __align__(16) f16_t Bsh[NF_*BK];    // 48 KB, swizzled chunks

  int tid  = threadIdx.x;          // 0..511
  int lane = tid & 63;
  int w    = tid >> 6;             // 0..7
  int wm   = (w >> 2) * 32;        // 0,32
  int wn   = (w & 3) * 96;         // 0,96,192,288
  int lr   = lane & 15;
  int lg   = lane >> 4;

  const float* xbase = x + (size_t)m0*V_;

  f32x4 acc[2][6] = {};

  for (int kt = 0; kt < NT_PROJ; kt++){
    #pragma unroll
    for (int i=0;i<6;i++){
      int ci = i*512 + tid;
      int r  = ci >> 3, ch = ci & 7;
      const f16_t* src = Wt + (size_t)r*V_ + kt*BK + ((ch ^ (r&7))<<3);
      gload_lds16(src, &Bsh[ci*8]);
    }
    #pragma unroll
    for (int i=0;i<2;i++){
      int ci = i*512 + tid;
      int row = ci >> 4, q = ci & 15;
      float4 xv = *(const float4*)(xbase + (size_t)row*V_ + kt*BK + q*4);
      union { f16_t h[4]; ushort4 u; } hh;
      hh.h[0]=(f16_t)xv.x; hh.h[1]=(f16_t)xv.y; hh.h[2]=(f16_t)xv.z; hh.h[3]=(f16_t)xv.w;
      *(ushort4*)&As[row][q*4] = hh.u;
    }
    __syncthreads();

    #pragma unroll
    for (int kh=0; kh<2; kh++){
      f16x8 a[2];
      #pragma unroll
      for (int mt=0; mt<2; mt++)
        a[mt] = *(f16x8*)&As[wm + mt*16 + lr][kh*32 + lg*8];
      #pragma unroll
      for (int nt=0; nt<6; nt++){
        int n  = wn + nt*16 + lr;
        int c0 = kh*4 + lg;
        f16x8 b = *(f16x8*)&Bsh[n*BK + ((c0 ^ (n&7))<<3)];
        #pragma unroll
        for (int mt=0; mt<2; mt++)
          acc[mt][nt] = __builtin_amdgcn_mfma_f32_16x16x32_f16(a[mt], b, acc[mt][nt], 0,0,0);
      }
    }
    __syncthreads();
  }

  #pragma unroll
  for (int mt=0; mt<2; mt++)
    #pragma unroll
    for (int nt=0; nt<6; nt++){
      int n   = wn + nt*16 + lr;
      int p   = n >> 7;
      int col = n & 127;
      float* op = out + (size_t)p*M*C_;
      #pragma unroll
      for (int r=0; r<4; r++){
        int row = m0 + wm + mt*16 + lg*4 + r;
        op[(size_t)row*C_ + col] = acc[mt][nt][r];
      }
    }
}

// ---------------------------------------------------------------------------
// K2: per-chunk KV summary: kv[b][ci][c][dd] = sum_j d^{L-1-j} k_j[c] v_j[dd]
// ---------------------------------------------------------------------------
__global__ __launch_bounds__(256) void kvsum_kernel(
    const float* __restrict__ k, const float* __restrict__ v,
    const float* __restrict__ dptr, float* __restrict__ kv)
{
  int ci = blockIdx.x, b = blockIdx.y;
  float d = sigmoidf_(dptr[0]);
  __shared__ float ks[L_][132];
  __shared__ float vs[L_][132];
  int tid = threadIdx.x;
  const float* kp = k + ((size_t)b*T_ + ci*L_)*C_;
  const float* vp = v + ((size_t)b*T_ + ci*L_)*C_;
  #pragma unroll
  for (int i=0;i<4;i++){
    int idx = tid + i*256;
    int j = idx >> 5, c4 = idx & 31;
    float w = powf(d, (float)(L_-1-j));
    float4 k4 = *(const float4*)(kp + (size_t)j*C_ + c4*4);
    k4.x*=w; k4.y*=w; k4.z*=w; k4.w*=w;
    *(float4*)&ks[j][c4*4] = k4;
    *(float4*)&vs[j][c4*4] = *(const float4*)(vp + (size_t)j*C_ + c4*4);
  }
  __syncthreads();
  int tc = tid >> 4, td = tid & 15;
  float acc[8][8] = {};
  for (int j=0;j<L_;j++){
    float kr[8], vr[8];
    *(float4*)&kr[0] = *(float4*)&ks[j][tc*8];
    *(float4*)&kr[4] = *(float4*)&ks[j][tc*8+4];
    *(float4*)&vr[0] = *(float4*)&vs[j][td*8];
    *(float4*)&vr[4] = *(float4*)&vs[j][td*8+4];
    #pragma unroll
    for (int a=0;a<8;a++)
      #pragma unroll
      for (int bb=0;bb<8;bb++) acc[a][bb] += kr[a]*vr[bb];
  }
  float* op = kv + ((size_t)b*NC_ + ci)*C_*C_;
  for (int a=0;a<8;a++)
    for (int b4=0;b4<2;b4++)
      *(float4*)(op + (size_t)(tc*8+a)*C_ + td*8 + b4*4) =
        make_float4(acc[a][b4*4],acc[a][b4*4+1],acc[a][b4*4+2],acc[a][b4*4+3]);
}

// ---------------------------------------------------------------------------
// K3: in-place exclusive scan over chunks
// ---------------------------------------------------------------------------
__global__ __launch_bounds__(256) void scan_kernel(
    float* __restrict__ kv, const float* __restrict__ dptr)
{
  int idx = blockIdx.x*256 + threadIdx.x;
  int b = idx >> 14, e = idx & 16383;
  float d  = sigmoidf_(dptr[0]);
  float dL = powf(d, (float)L_);
  float* p = kv + (size_t)b*NC_*C_*C_ + e;
  float m = 0.f;
  for (int i=0;i<NC_;i++){
    float s = p[(size_t)i*C_*C_];
    p[(size_t)i*C_*C_] = m;
    m = dL*m + s;
  }
}

// ---------------------------------------------------------------------------
// K4: per-chunk retrieved; epilogue writes ret as fp16 (feeds out MFMA).
// M streamed through LDS in 4 chunks of 32 rows, coalesced, double-buffered
// with the next chunk held in 16 regs across one barrier.
// ---------------------------------------------------------------------------
__global__ __launch_bounds__(256, 3) void intra_kernel(
    const float* __restrict__ q, const float* __restrict__ k,
    const float* __restrict__ v, const float* __restrict__ Minit,
    const float* __restrict__ dptr,
    f16_t* __restrict__ ret)
{
  int ci = blockIdx.x, b = blockIdx.y;
  int tid = threadIdx.x;
  float d = sigmoidf_(dptr[0]);
  __shared__ float qs[L_][132];
  __shared__ float kvs[L_][132];       // k for scores, then v
  __shared__ float Ms[2][L_][C_];      // 32 KB, unpadded: row-contig reads
  __shared__ float ps[L_][33];
  __shared__ float dpow[L_+1];
  if (tid <= L_) dpow[tid] = powf(d, (float)tid);

  const float* qp = q + ((size_t)b*T_ + ci*L_)*C_;
  const float* kp = k + ((size_t)b*T_ + ci*L_)*C_;
  const float* vp = v + ((size_t)b*T_ + ci*L_)*C_;
  const float* Mp = Minit + ((size_t)b*NC_ + ci)*C_*C_;

  int mr0 = tid >> 5;   // 0..7  (M-chunk row base; rows mr0+8i)
  int mc4 = tid & 31;   // float4 col

  float4 mreg[4];
  // issue chunk-0 M loads (coalesced, no redundancy)
  #pragma unroll
  for (int i=0;i<4;i++)
    mreg[i] = *(const float4*)(Mp + (size_t)(mr0 + i*8)*C_ + mc4*4);

  #pragma unroll
  for (int i=0;i<4;i++){
    int idx = tid + i*256;
    int j = idx >> 5, c4 = idx & 31;
    *(float4*)&qs[j][c4*4]  = *(const float4*)(qp + (size_t)j*C_ + c4*4);
    *(float4*)&kvs[j][c4*4] = *(const float4*)(kp + (size_t)j*C_ + c4*4);
  }
  __syncthreads();   // B0: qs, kvs(k) visible

  // ---- scores ps
  {
    int tr = tid >> 4, tj = tid & 15;
    float s[2][2] = {};
    for (int c4=0;c4<32;c4++){
      float4 q4[2], k4[2];
      #pragma unroll
      for (int i=0;i<2;i++) q4[i] = *(float4*)&qs[tr*2+i][c4*4];
      #pragma unroll
      for (int i=0;i<2;i++) k4[i] = *(float4*)&kvs[tj*2+i][c4*4];
      #pragma unroll
      for (int a=0;a<2;a++)
        #pragma unroll
        for (int bb=0;bb<2;bb++)
          s[a][bb] += q4[a].x*k4[bb].x + q4[a].y*k4[bb].y + q4[a].z*k4[bb].z + q4[a].w*k4[bb].w;
    }
    #pragma unroll
    for (int a=0;a<2;a++)
      #pragma unroll
      for (int bb=0;bb<2;bb++){
        int r = tr*2+a, j = tj*2+bb;
        ps[r][j] = (j < r) ? s[a][bb]*dpow[r-1-j] : 0.f;
      }
  }
  // write chunk 0 to Ms[0]; prefetch chunk 1
  #pragma unroll
  for (int i=0;i<4;i++) *(float4*)&Ms[0][mr0 + i*8][mc4*4] = mreg[i];
  #pragma unroll
  for (int i=0;i<4;i++)
    mreg[i] = *(const float4*)(Mp + (size_t)(L_ + mr0 + i*8)*C_ + mc4*4);
  __syncthreads();   // B1: ps, Ms[0] visible; kvs(k) dead

  // v -> kvs (read after B2+)
  #pragma unroll
  for (int i=0;i<4;i++){
    int idx = tid + i*256;
    int j = idx >> 5, c4 = idx & 31;
    *(float4*)&kvs[j][c4*4] = *(const float4*)(vp + (size_t)j*C_ + c4*4);
  }

  int tx = tid & 31, ty = tid >> 5;
  float acc[4][4] = {};

#define INTRA_MCHUNK(buf, cc) do { \
    for (int c=0;c<L_;c++){ \
      float4 m4 = *(float4*)&Ms[buf][c][tx*4]; \
      _Pragma("unroll") \
      for (int r=0;r<4;r++){ \
        float qv = qs[ty*4+r][(cc)*L_ + c]; \
        acc[r][0] += qv*m4.x; acc[r][1] += qv*m4.y; \
        acc[r][2] += qv*m4.z; acc[r][3] += qv*m4.w; \
      } \
    } \
  } while(0)

  INTRA_MCHUNK(0, 0);
  #pragma unroll
  for (int i=0;i<4;i++) *(float4*)&Ms[1][mr0 + i*8][mc4*4] = mreg[i];
  #pragma unroll
  for (int i=0;i<4;i++)
    mreg[i] = *(const float4*)(Mp + (size_t)(2*L_ + mr0 + i*8)*C_ + mc4*4);
  __syncthreads();   // B2: Ms[1], kvs(v) visible

  INTRA_MCHUNK(1, 1);
  #pragma unroll
  for (int i=0;i<4;i++) *(float4*)&Ms[0][mr0 + i*8][mc4*4] = mreg[i];
  #pragma unroll
  for (int i=0;i<4;i++)
    mreg[i] = *(const float4*)(Mp + (size_t)(3*L_ + mr0 + i*8)*C_ + mc4*4);
  __syncthreads();   // B3: Ms[0]=chunk2 visible

  INTRA_MCHUNK(0, 2);
  #pragma unroll
  for (int i=0;i<4;i++) *(float4*)&Ms[1][mr0 + i*8][mc4*4] = mreg[i];
  __syncthreads();   // B4: Ms[1]=chunk3 visible

  INTRA_MCHUNK(1, 3);
#undef INTRA_MCHUNK

  #pragma unroll
  for (int r=0;r<4;r++){
    float sc = dpow[ty*4+r];
    #pragma unroll
    for (int j=0;j<4;j++) acc[r][j] *= sc;
  }
  for (int j=0;j<L_;j++){
    float4 v4 = *(float4*)&kvs[j][tx*4];
    #pragma unroll
    for (int r=0;r<4;r++){
      float p = ps[ty*4+r][j];
      acc[r][0] += p*v4.x; acc[r][1] += p*v4.y; acc[r][2] += p*v4.z; acc[r][3] += p*v4.w;
    }
  }
  size_t rbase = ((size_t)b*T_ + ci*L_)*C_;
  for (int r=0;r<4;r++){
    union { f16_t h[4]; ushort4 u; } hh;
    #pragma unroll
    for (int j=0;j<4;j++) hh.h[j] = (f16_t)acc[r][j];
    *(ushort4*)(ret + rbase + (size_t)(ty*4+r)*C_ + tx*4) = hh.u;
  }
}

// ---------------------------------------------------------------------------
// K5: out = (ret @ Wo^T) * out_scale, single-term fp16 MFMA.
// M=16384, N=1024, K=128. BM=64, BN=128, kt loop 2x BK=64. grid (256,8).
// ---------------------------------------------------------------------------
__global__ __launch_bounds__(256, 2) void out_mfma_kernel(
    const f16_t* __restrict__ A, const f16_t* __restrict__ Bw,
    const float* __restrict__ scl, float* __restrict__ out)
{
  int m0 = blockIdx.x * BM;
  int n0 = blockIdx.y * BN;
  float osc = scl[0];

  __shared__ f16_t As[BM][PADK];
  __shared__ f16_t Bs[BN][PADK];

  int tid  = threadIdx.x;
  int lane = tid & 63;
  int w    = tid >> 6;
  int wm   = (w >> 1) * 32;
  int wn   = (w & 1) * 64;
  int lr   = lane & 15;
  int lg   = lane >> 4;

  f32x4 acc[2][4] = {};

  for (int kt = 0; kt < 2; kt++){
    #pragma unroll
    for (int i=0;i<2;i++){
      int ci = tid + i*256;
      int row = ci >> 3, ch = ci & 7;
      *(uint4*)&As[row][ch*8] = *(const uint4*)(A + (size_t)(m0+row)*C_ + kt*BK + ch*8);
    }
    #pragma unroll
    for (int i=0;i<4;i++){
      int ci = tid + i*256;
      int n = ci >> 3, ch = ci & 7;
      *(uint4*)&Bs[n][ch*8] = *(const uint4*)(Bw + (size_t)(n0+n)*C_ + kt*BK + ch*8);
    }
    __syncthreads();

    #pragma unroll
    for (int kh=0; kh<2; kh++){
      f16x8 a[2];
      #pragma unroll
      for (int mt=0; mt<2; mt++)
        a[mt] = *(f16x8*)&As[wm + mt*16 + lr][kh*32 + lg*8];
      #pragma unroll
      for (int nt=0; nt<4; nt++){
        f16x8 b = *(f16x8*)&Bs[wn + nt*16 + lr][kh*32 + lg*8];
        #pragma unroll
        for (int mt=0; mt<2; mt++)
          acc[mt][nt] = __builtin_amdgcn_mfma_f32_16x16x32_f16(a[mt], b, acc[mt][nt], 0,0,0);
      }
    }
    __syncthreads();
  }

  #pragma unroll
  for (int mt=0; mt<2; mt++)
    #pragma unroll
    for (int nt=0; nt<4; nt++)
      #pragma unroll
      for (int r=0; r<4; r++){
        int row = m0 + wm + mt*16 + lg*4 + r;
        int col = n0 + wn + nt*16 + lr;
        out[(size_t)row*V_ + col] = acc[mt][nt][r] * osc;
      }
}

// ---------------------------------------------------------------------------
extern "C" void kernel_launch(void* const* d_in, const int* in_sizes, int n_in,
                              void* d_out, int out_size, void* d_ws, size_t ws_size,
                              hipStream_t stream)
{
  const float* x     = (const float*)d_in[0];
  const float* basis = (const float*)d_in[1];
  const float* qc    = (const float*)d_in[2];
  const float* kc    = (const float*)d_in[3];
  const float* vc    = (const float*)d_in[4];
  const float* oc    = (const float*)d_in[5];
  const float* dptr  = (const float*)d_in[6];
  const float* sptr  = (const float*)d_in[7];
  float* out = (float*)d_out;
  float* ws  = (float*)d_ws;

  const size_t M = (size_t)B_*T_;
  // Workspace layout (offsets in FLOAT units):
  //   Wo   f16 V*C      @ 0        (65536 f)
  //   Wt   f16 3*C*V    @ 65536    (196608 f)
  //   qkv  f32 3*M*C    @ 262144
  //   ret  f16 M*C      @ 6553600
  //   kv   f32 B*NC*C*C @ 7602176
  f16_t* Wo  = (f16_t*)ws;
  f16_t* Wt  = (f16_t*)(ws + 65536);
  float* qkv = ws + 262144;
  f16_t* ret = (f16_t*)(ws + 6553600);
  float* kv  = ws + 7602176;

  float* q = qkv;
  float* k = qkv + M*C_;
  float* v = qkv + 2*M*C_;

  hipLaunchKernelGGL(weights_kernel, dim3(512), dim3(256), 0, stream,
                     basis, qc, kc, vc, oc, Wo, Wt);
  hipLaunchKernelGGL(proj_fused_kernel, dim3(256), dim3(512), 0, stream,
                     x, Wt, qkv);
  hipLaunchKernelGGL(kvsum_kernel, dim3(NC_, B_), dim3(256), 0, stream, k, v, dptr, kv);
  hipLaunchKernelGGL(scan_kernel, dim3(512), dim3(256), 0, stream, kv, dptr);
  hipLaunchKernelGGL(intra_kernel, dim3(NC_, B_), dim3(256), 0, stream,
                     q, k, v, kv, dptr, ret);
  hipLaunchKernelGGL(out_mfma_kernel, dim3(256, 8), dim3(256), 0, stream,
                     ret, Wo, sptr, out);
}

// Round 5
// 240.766 us; speedup vs baseline: 1.2923x; 1.0369x over previous
//
#include <hip/hip_runtime.h>
#include <math.h>

// Problem constants
#define B_   8
#define T_   2048
#define V_   1024
#define C_   128
#define NB2  64     // 2*NB
#define L_   32     // chunk length for the linearized recurrence
#define NC_  64     // T_/L_

typedef _Float16 f16_t;
typedef f16_t f16x8 __attribute__((ext_vector_type(8)));
typedef float f32x4 __attribute__((ext_vector_type(4)));

__device__ __forceinline__ float sigmoidf_(float x){ return 1.0f/(1.0f+expf(-x)); }

// direct global->LDS DMA, 16 B per lane (dest must be linear: base + lane*16)
__device__ __forceinline__ void gload_lds16(const void* g, void* l){
  __builtin_amdgcn_global_load_lds(
      (const __attribute__((address_space(1))) uint32_t*)g,
      (__attribute__((address_space(3))) uint32_t*)l, 16, 0, 0);
}

// ---------------------------------------------------------------------------
// K0: weights. proj 0..2: softmax(basis@coeffs^T, axis=V) -> fp16,
//     TRANSPOSED (Wt[c][v]) for MFMA B-fragment reads.
//     proj 3: Wo (V,C) row-major fp16 (rows are B-fragments for out GEMM).
// ---------------------------------------------------------------------------
__global__ __launch_bounds__(256) void weights_kernel(
    const float* __restrict__ basis,
    const float* __restrict__ qc, const float* __restrict__ kc,
    const float* __restrict__ vc, const float* __restrict__ oc,
    f16_t* __restrict__ Wo, f16_t* __restrict__ Wt)
{
  int blk  = blockIdx.x;
  int proj = blk >> 7;
  int c    = blk & 127;
  const float* coeffs = (proj==0)?qc : (proj==1)?kc : (proj==2)?vc : oc;

  __shared__ float coef[NB2];
  __shared__ float red[256];
  int tid = threadIdx.x;
  if (tid < NB2) coef[tid] = coeffs[c*NB2 + tid];
  __syncthreads();

  float l[4];
  for (int i=0;i<4;i++){
    int v = tid + i*256;
    const float4* bp = (const float4*)(basis + (size_t)v*NB2);
    float s = 0.f;
    #pragma unroll
    for (int f=0; f<NB2/4; f++){
      float4 b4 = bp[f];
      s += b4.x*coef[f*4+0] + b4.y*coef[f*4+1] + b4.z*coef[f*4+2] + b4.w*coef[f*4+3];
    }
    l[i] = s;
  }
  if (proj == 3){
    for (int i=0;i<4;i++){ int v = tid+i*256; Wo[(size_t)v*C_ + c] = (f16_t)l[i]; }
    return;
  }
  float mx = fmaxf(fmaxf(l[0],l[1]), fmaxf(l[2],l[3]));
  red[tid] = mx; __syncthreads();
  for (int s=128; s>0; s>>=1){ if (tid<s) red[tid] = fmaxf(red[tid], red[tid+s]); __syncthreads(); }
  mx = red[0]; __syncthreads();
  float sum = 0.f;
  for (int i=0;i<4;i++) sum += expf(l[i]-mx);
  red[tid] = sum; __syncthreads();
  for (int s=128; s>0; s>>=1){ if (tid<s) red[tid] += red[tid+s]; __syncthreads(); }
  float inv = 1.0f/red[0];
  f16_t* tp = Wt + ((size_t)proj*C_ + c)*V_;
  for (int i=0;i<4;i++){
    int v = tid+i*256;
    tp[v] = (f16_t)(expf(l[i]-mx)*inv);
  }
}

// ---------------------------------------------------------------------------
// K1 (FUSED): q,k,v = x @ [Wq|Wk|Wv] in ONE pass over x.
// 512 thr = 8 waves (2x4), wave tile 32x96, BM=64, N=384, BK=64, 16 K-iters.
// B staged via global_load_lds (linear LDS, XOR-swizzled source + same XOR on
// ds_read). LDS 57.6 KB, grid 256 = 1 block/CU.
// ---------------------------------------------------------------------------
#define BM 64
#define BN 128
#define BK 64
#define PADK 72   // LDS row stride in f16 for A (144 B, breaks pow2 banks)
#define NF_  384  // 3*C
#define NT_PROJ (V_/BK)   // 16

__global__ __launch_bounds__(512, 1) void proj_fused_kernel(
    const float* __restrict__ x,
    const f16_t* __restrict__ Wt,   // [384][1024] f16 (= [3][C][V])
    float* __restrict__ out)        // [3][M][C]
{
  const int M = B_*T_;
  int m0 = blockIdx.x * BM;

  __shared__ __align__(16) f16_t As[BM][PADK];   // 9.2 KB
  __shared__ __align__(16) f16_t Bsh[NF_*BK];    // 48 KB, swizzled chunks

  int tid  = threadIdx.x;          // 0..511
  int lane = tid & 63;
  int w    = tid >> 6;             // 0..7
  int wm   = (w >> 2) * 32;        // 0,32
  int wn   = (w & 3) * 96;         // 0,96,192,288
  int lr   = lane & 15;
  int lg   = lane >> 4;

  const float* xbase = x + (size_t)m0*V_;

  f32x4 acc[2][6] = {};

  for (int kt = 0; kt < NT_PROJ; kt++){
    #pragma unroll
    for (int i=0;i<6;i++){
      int ci = i*512 + tid;
      int r  = ci >> 3, ch = ci & 7;
      const f16_t* src = Wt + (size_t)r*V_ + kt*BK + ((ch ^ (r&7))<<3);
      gload_lds16(src, &Bsh[ci*8]);
    }
    #pragma unroll
    for (int i=0;i<2;i++){
      int ci = i*512 + tid;
      int row = ci >> 4, q = ci & 15;
      float4 xv = *(const float4*)(xbase + (size_t)row*V_ + kt*BK + q*4);
      union { f16_t h[4]; ushort4 u; } hh;
      hh.h[0]=(f16_t)xv.x; hh.h[1]=(f16_t)xv.y; hh.h[2]=(f16_t)xv.z; hh.h[3]=(f16_t)xv.w;
      *(ushort4*)&As[row][q*4] = hh.u;
    }
    __syncthreads();

    #pragma unroll
    for (int kh=0; kh<2; kh++){
      f16x8 a[2];
      #pragma unroll
      for (int mt=0; mt<2; mt++)
        a[mt] = *(f16x8*)&As[wm + mt*16 + lr][kh*32 + lg*8];
      #pragma unroll
      for (int nt=0; nt<6; nt++){
        int n  = wn + nt*16 + lr;
        int c0 = kh*4 + lg;
        f16x8 b = *(f16x8*)&Bsh[n*BK + ((c0 ^ (n&7))<<3)];
        #pragma unroll
        for (int mt=0; mt<2; mt++)
          acc[mt][nt] = __builtin_amdgcn_mfma_f32_16x16x32_f16(a[mt], b, acc[mt][nt], 0,0,0);
      }
    }
    __syncthreads();
  }

  #pragma unroll
  for (int mt=0; mt<2; mt++)
    #pragma unroll
    for (int nt=0; nt<6; nt++){
      int n   = wn + nt*16 + lr;
      int p   = n >> 7;
      int col = n & 127;
      float* op = out + (size_t)p*M*C_;
      #pragma unroll
      for (int r=0; r<4; r++){
        int row = m0 + wm + mt*16 + lg*4 + r;
        op[(size_t)row*C_ + col] = acc[mt][nt][r];
      }
    }
}

// ---------------------------------------------------------------------------
// K2: per-chunk KV summary: kv[b][ci][c][dd] = sum_j d^{L-1-j} k_j[c] v_j[dd]
// ---------------------------------------------------------------------------
__global__ __launch_bounds__(256) void kvsum_kernel(
    const float* __restrict__ k, const float* __restrict__ v,
    const float* __restrict__ dptr, float* __restrict__ kv)
{
  int ci = blockIdx.x, b = blockIdx.y;
  float d = sigmoidf_(dptr[0]);
  __shared__ float ks[L_][132];
  __shared__ float vs[L_][132];
  int tid = threadIdx.x;
  const float* kp = k + ((size_t)b*T_ + ci*L_)*C_;
  const float* vp = v + ((size_t)b*T_ + ci*L_)*C_;
  #pragma unroll
  for (int i=0;i<4;i++){
    int idx = tid + i*256;
    int j = idx >> 5, c4 = idx & 31;
    float w = powf(d, (float)(L_-1-j));
    float4 k4 = *(const float4*)(kp + (size_t)j*C_ + c4*4);
    k4.x*=w; k4.y*=w; k4.z*=w; k4.w*=w;
    *(float4*)&ks[j][c4*4] = k4;
    *(float4*)&vs[j][c4*4] = *(const float4*)(vp + (size_t)j*C_ + c4*4);
  }
  __syncthreads();
  int tc = tid >> 4, td = tid & 15;
  float acc[8][8] = {};
  for (int j=0;j<L_;j++){
    float kr[8], vr[8];
    *(float4*)&kr[0] = *(float4*)&ks[j][tc*8];
    *(float4*)&kr[4] = *(float4*)&ks[j][tc*8+4];
    *(float4*)&vr[0] = *(float4*)&vs[j][td*8];
    *(float4*)&vr[4] = *(float4*)&vs[j][td*8+4];
    #pragma unroll
    for (int a=0;a<8;a++)
      #pragma unroll
      for (int bb=0;bb<8;bb++) acc[a][bb] += kr[a]*vr[bb];
  }
  float* op = kv + ((size_t)b*NC_ + ci)*C_*C_;
  for (int a=0;a<8;a++)
    for (int b4=0;b4<2;b4++)
      *(float4*)(op + (size_t)(tc*8+a)*C_ + td*8 + b4*4) =
        make_float4(acc[a][b4*4],acc[a][b4*4+1],acc[a][b4*4+2],acc[a][b4*4+3]);
}

// ---------------------------------------------------------------------------
// K3: in-place exclusive scan over chunks
// ---------------------------------------------------------------------------
__global__ __launch_bounds__(256) void scan_kernel(
    float* __restrict__ kv, const float* __restrict__ dptr)
{
  int idx = blockIdx.x*256 + threadIdx.x;
  int b = idx >> 14, e = idx & 16383;
  float d  = sigmoidf_(dptr[0]);
  float dL = powf(d, (float)L_);
  float* p = kv + (size_t)b*NC_*C_*C_ + e;
  float m = 0.f;
  for (int i=0;i<NC_;i++){
    float s = p[(size_t)i*C_*C_];
    p[(size_t)i*C_*C_] = m;
    m = dL*m + s;
  }
}

// ---------------------------------------------------------------------------
// K4: per-chunk retrieved; epilogue writes ret as fp16 (feeds out MFMA).
// v3: M chunks staged via global_load_lds DMA (zero VGPR cost -- the round-1
// and round-4 register-prefetch attempts both SPILLED, WRITE_SIZE tripwire).
// M chunk = 32 contiguous rows x 128 cols = contiguous 16 KB: dest is exactly
// uniform+lane*16 (DMA-legal, linear). Chunk k+1's DMA is issued right after
// the barrier that frees its buffer and drains at the NEXT barrier, hidden
// under chunk k's ~2000 cy of FMA.
// ---------------------------------------------------------------------------
__global__ __launch_bounds__(256, 4) void intra_kernel(
    const float* __restrict__ q, const float* __restrict__ k,
    const float* __restrict__ v, const float* __restrict__ Minit,
    const float* __restrict__ dptr,
    f16_t* __restrict__ ret)
{
  int ci = blockIdx.x, b = blockIdx.y;
  int tid = threadIdx.x;
  float d = sigmoidf_(dptr[0]);
  __shared__ float qs[L_][132];
  __shared__ float kvs[L_][132];            // k for scores, then v
  __shared__ __align__(16) float Ms[2][L_][C_];  // 32 KB, linear (DMA dest)
  __shared__ float ps[L_][33];
  __shared__ float dpow[L_+1];
  if (tid <= L_) dpow[tid] = powf(d, (float)tid);

  const float* qp = q + ((size_t)b*T_ + ci*L_)*C_;
  const float* kp = k + ((size_t)b*T_ + ci*L_)*C_;
  const float* vp = v + ((size_t)b*T_ + ci*L_)*C_;
  const float* Mp = Minit + ((size_t)b*NC_ + ci)*C_*C_;

  // ---- DMA chunk 0 -> Ms[0] (16 KB = 1024 x 16B, 4 per thread)
  #pragma unroll
  for (int i=0;i<4;i++){
    int cidx = i*256 + tid;
    gload_lds16(Mp + (size_t)cidx*4, &Ms[0][0][cidx*4]);
  }
  // ---- stage q, k
  #pragma unroll
  for (int i=0;i<4;i++){
    int idx = tid + i*256;
    int j = idx >> 5, c4 = idx & 31;
    *(float4*)&qs[j][c4*4]  = *(const float4*)(qp + (size_t)j*C_ + c4*4);
    *(float4*)&kvs[j][c4*4] = *(const float4*)(kp + (size_t)j*C_ + c4*4);
  }
  __syncthreads();   // B0: chunk0 + qs + kvs(k) visible

  // ---- DMA chunk 1 -> Ms[1] (drains at B1, hidden under scores)
  #pragma unroll
  for (int i=0;i<4;i++){
    int cidx = i*256 + tid;
    gload_lds16(Mp + (size_t)L_*C_ + cidx*4, &Ms[1][0][cidx*4]);
  }

  // ---- scores ps
  {
    int tr = tid >> 4, tj = tid & 15;
    float s[2][2] = {};
    for (int c4=0;c4<32;c4++){
      float4 q4[2], k4[2];
      #pragma unroll
      for (int i=0;i<2;i++) q4[i] = *(float4*)&qs[tr*2+i][c4*4];
      #pragma unroll
      for (int i=0;i<2;i++) k4[i] = *(float4*)&kvs[tj*2+i][c4*4];
      #pragma unroll
      for (int a=0;a<2;a++)
        #pragma unroll
        for (int bb=0;bb<2;bb++)
          s[a][bb] += q4[a].x*k4[bb].x + q4[a].y*k4[bb].y + q4[a].z*k4[bb].z + q4[a].w*k4[bb].w;
    }
    #pragma unroll
    for (int a=0;a<2;a++)
      #pragma unroll
      for (int bb=0;bb<2;bb++){
        int r = tr*2+a, j = tj*2+bb;
        ps[r][j] = (j < r) ? s[a][bb]*dpow[r-1-j] : 0.f;
      }
  }
  __syncthreads();   // B1: ps + chunk1 visible; kvs(k) dead

  // ---- stage v into kvs (read only after B2; its loads overlap MCHUNK(0,0))
  #pragma unroll
  for (int i=0;i<4;i++){
    int idx = tid + i*256;
    int j = idx >> 5, c4 = idx & 31;
    *(float4*)&kvs[j][c4*4] = *(const float4*)(vp + (size_t)j*C_ + c4*4);
  }

  int tx = tid & 31, ty = tid >> 5;
  float acc[4][4] = {};

#define INTRA_MCHUNK(buf, cc) do { \
    for (int c=0;c<L_;c++){ \
      float4 m4 = *(float4*)&Ms[buf][c][tx*4]; \
      _Pragma("unroll") \
      for (int r=0;r<4;r++){ \
        float qv = qs[ty*4+r][(cc)*L_ + c]; \
        acc[r][0] += qv*m4.x; acc[r][1] += qv*m4.y; \
        acc[r][2] += qv*m4.z; acc[r][3] += qv*m4.w; \
      } \
    } \
  } while(0)

  INTRA_MCHUNK(0, 0);
  __syncthreads();   // B2: Ms[0] reads done; kvs(v) visible

  // ---- DMA chunk 2 -> Ms[0] (drains at B3, hidden under MCHUNK(1,1))
  #pragma unroll
  for (int i=0;i<4;i++){
    int cidx = i*256 + tid;
    gload_lds16(Mp + (size_t)2*L_*C_ + cidx*4, &Ms[0][0][cidx*4]);
  }
  INTRA_MCHUNK(1, 1);
  __syncthreads();   // B3: chunk2 visible; Ms[1] reads done

  // ---- DMA chunk 3 -> Ms[1] (drains at B4, hidden under MCHUNK(0,2))
  #pragma unroll
  for (int i=0;i<4;i++){
    int cidx = i*256 + tid;
    gload_lds16(Mp + (size_t)3*L_*C_ + cidx*4, &Ms[1][0][cidx*4]);
  }
  INTRA_MCHUNK(0, 2);
  __syncthreads();   // B4: chunk3 visible

  INTRA_MCHUNK(1, 3);
#undef INTRA_MCHUNK

  #pragma unroll
  for (int r=0;r<4;r++){
    float sc = dpow[ty*4+r];
    #pragma unroll
    for (int j=0;j<4;j++) acc[r][j] *= sc;
  }
  for (int j=0;j<L_;j++){
    float4 v4 = *(float4*)&kvs[j][tx*4];
    #pragma unroll
    for (int r=0;r<4;r++){
      float p = ps[ty*4+r][j];
      acc[r][0] += p*v4.x; acc[r][1] += p*v4.y; acc[r][2] += p*v4.z; acc[r][3] += p*v4.w;
    }
  }
  size_t rbase = ((size_t)b*T_ + ci*L_)*C_;
  for (int r=0;r<4;r++){
    union { f16_t h[4]; ushort4 u; } hh;
    #pragma unroll
    for (int j=0;j<4;j++) hh.h[j] = (f16_t)acc[r][j];
    *(ushort4*)(ret + rbase + (size_t)(ty*4+r)*C_ + tx*4) = hh.u;
  }
}

// ---------------------------------------------------------------------------
// K5: out = (ret @ Wo^T) * out_scale, single-term fp16 MFMA.
// M=16384, N=1024, K=128. BM=64, BN=128, kt loop 2x BK=64. grid (256,8).
// ---------------------------------------------------------------------------
__global__ __launch_bounds__(256, 2) void out_mfma_kernel(
    const f16_t* __restrict__ A, const f16_t* __restrict__ Bw,
    const float* __restrict__ scl, float* __restrict__ out)
{
  int m0 = blockIdx.x * BM;
  int n0 = blockIdx.y * BN;
  float osc = scl[0];

  __shared__ f16_t As[BM][PADK];
  __shared__ f16_t Bs[BN][PADK];

  int tid  = threadIdx.x;
  int lane = tid & 63;
  int w    = tid >> 6;
  int wm   = (w >> 1) * 32;
  int wn   = (w & 1) * 64;
  int lr   = lane & 15;
  int lg   = lane >> 4;

  f32x4 acc[2][4] = {};

  for (int kt = 0; kt < 2; kt++){
    #pragma unroll
    for (int i=0;i<2;i++){
      int ci = tid + i*256;
      int row = ci >> 3, ch = ci & 7;
      *(uint4*)&As[row][ch*8] = *(const uint4*)(A + (size_t)(m0+row)*C_ + kt*BK + ch*8);
    }
    #pragma unroll
    for (int i=0;i<4;i++){
      int ci = tid + i*256;
      int n = ci >> 3, ch = ci & 7;
      *(uint4*)&Bs[n][ch*8] = *(const uint4*)(Bw + (size_t)(n0+n)*C_ + kt*BK + ch*8);
    }
    __syncthreads();

    #pragma unroll
    for (int kh=0; kh<2; kh++){
      f16x8 a[2];
      #pragma unroll
      for (int mt=0; mt<2; mt++)
        a[mt] = *(f16x8*)&As[wm + mt*16 + lr][kh*32 + lg*8];
      #pragma unroll
      for (int nt=0; nt<4; nt++){
        f16x8 b = *(f16x8*)&Bs[wn + nt*16 + lr][kh*32 + lg*8];
        #pragma unroll
        for (int mt=0; mt<2; mt++)
          acc[mt][nt] = __builtin_amdgcn_mfma_f32_16x16x32_f16(a[mt], b, acc[mt][nt], 0,0,0);
      }
    }
    __syncthreads();
  }

  #pragma unroll
  for (int mt=0; mt<2; mt++)
    #pragma unroll
    for (int nt=0; nt<4; nt++)
      #pragma unroll
      for (int r=0; r<4; r++){
        int row = m0 + wm + mt*16 + lg*4 + r;
        int col = n0 + wn + nt*16 + lr;
        out[(size_t)row*V_ + col] = acc[mt][nt][r] * osc;
      }
}

// ---------------------------------------------------------------------------
extern "C" void kernel_launch(void* const* d_in, const int* in_sizes, int n_in,
                              void* d_out, int out_size, void* d_ws, size_t ws_size,
                              hipStream_t stream)
{
  const float* x     = (const float*)d_in[0];
  const float* basis = (const float*)d_in[1];
  const float* qc    = (const float*)d_in[2];
  const float* kc    = (const float*)d_in[3];
  const float* vc    = (const float*)d_in[4];
  const float* oc    = (const float*)d_in[5];
  const float* dptr  = (const float*)d_in[6];
  const float* sptr  = (const float*)d_in[7];
  float* out = (float*)d_out;
  float* ws  = (float*)d_ws;

  const size_t M = (size_t)B_*T_;
  // Workspace layout (offsets in FLOAT units):
  //   Wo   f16 V*C      @ 0        (65536 f)
  //   Wt   f16 3*C*V    @ 65536    (196608 f)
  //   qkv  f32 3*M*C    @ 262144
  //   ret  f16 M*C      @ 6553600
  //   kv   f32 B*NC*C*C @ 7602176
  f16_t* Wo  = (f16_t*)ws;
  f16_t* Wt  = (f16_t*)(ws + 65536);
  float* qkv = ws + 262144;
  f16_t* ret = (f16_t*)(ws + 6553600);
  float* kv  = ws + 7602176;

  float* q = qkv;
  float* k = qkv + M*C_;
  float* v = qkv + 2*M*C_;

  hipLaunchKernelGGL(weights_kernel, dim3(512), dim3(256), 0, stream,
                     basis, qc, kc, vc, oc, Wo, Wt);
  hipLaunchKernelGGL(proj_fused_kernel, dim3(256), dim3(512), 0, stream,
                     x, Wt, qkv);
  hipLaunchKernelGGL(kvsum_kernel, dim3(NC_, B_), dim3(256), 0, stream, k, v, dptr, kv);
  hipLaunchKernelGGL(scan_kernel, dim3(512), dim3(256), 0, stream, kv, dptr);
  hipLaunchKernelGGL(intra_kernel, dim3(NC_, B_), dim3(256), 0, stream,
                     q, k, v, kv, dptr, ret);
  hipLaunchKernelGGL(out_mfma_kernel, dim3(256, 8), dim3(256), 0, stream,
                     ret, Wo, sptr, out);
}